// Round 1
// baseline (843.560 us; speedup 1.0000x reference)
//
#include <hip/hip_runtime.h>

// MoE top-2, D=1024, DFF=4096, E=8, T=4096. Sparse grouped-GEMM in bf16 MFMA.

#define T_TOK 4096
#define DMODEL 1024
#define DFF 4096
#define NE 8
#define CAP 9216            // max aligned slots: 8192 + 8*127 -> 9208, padded
#define MT_CAP (CAP / 128)  // 72

typedef __bf16 bf16x8 __attribute__((ext_vector_type(8)));
typedef float f32x4 __attribute__((ext_vector_type(4)));

__device__ __forceinline__ unsigned short f2bf(float f) {
    union { float f; unsigned u; } v; v.f = f;
    unsigned r = v.u + 0x7fffu + ((v.u >> 16) & 1u);
    return (unsigned short)(r >> 16);
}

// meta layout (ints): [0..7] count, [8..15] cursor, [16..23] aligned, [24..32] off[9], [33] total
__global__ __launch_bounds__(256) void k_router(const float* __restrict__ x,
                                                const float* __restrict__ Wr,
                                                int* __restrict__ meta,
                                                int* __restrict__ tg_idx,
                                                float* __restrict__ tg_gate) {
    int wave = threadIdx.x >> 6, lane = threadIdx.x & 63;
    int t = blockIdx.x * 4 + wave;
    double acc[NE];
#pragma unroll
    for (int e = 0; e < NE; e++) acc[e] = 0.0;
    const float* xr = x + (size_t)t * DMODEL;
#pragma unroll 4
    for (int j = 0; j < 16; j++) {
        int k = j * 64 + lane;
        double xv = (double)xr[k];
        const float4* wr = (const float4*)(Wr + k * NE);
        float4 w0 = wr[0], w1 = wr[1];
        acc[0] += xv * (double)w0.x; acc[1] += xv * (double)w0.y;
        acc[2] += xv * (double)w0.z; acc[3] += xv * (double)w0.w;
        acc[4] += xv * (double)w1.x; acc[5] += xv * (double)w1.y;
        acc[6] += xv * (double)w1.z; acc[7] += xv * (double)w1.w;
    }
#pragma unroll
    for (int off = 32; off; off >>= 1)
#pragma unroll
        for (int e = 0; e < NE; e++) acc[e] += __shfl_xor(acc[e], off);
    if (lane == 0) {
        double v1 = -1e300, v2 = -1e300; int i1 = 0, i2 = 0;
#pragma unroll
        for (int e = 0; e < NE; e++) {
            double v = acc[e];
            if (v > v1) { v2 = v1; i2 = i1; v1 = v; i1 = e; }
            else if (v > v2) { v2 = v; i2 = e; }
        }
        double g1 = 1.0 / (1.0 + exp(v2 - v1));
        tg_idx[t * 2] = i1; tg_idx[t * 2 + 1] = i2;
        tg_gate[t * 2] = (float)g1; tg_gate[t * 2 + 1] = (float)(1.0 - g1);
        atomicAdd(&meta[i1], 1);
        atomicAdd(&meta[i2], 1);
    }
}

__global__ void k_scan(int* __restrict__ meta) {
    if (threadIdx.x == 0) {
        int acc = 0;
        for (int e = 0; e < NE; e++) {
            int a = (meta[e] + 127) & ~127;
            meta[16 + e] = a;
            meta[24 + e] = acc;
            acc += a;
        }
        meta[24 + NE] = acc;
        meta[33] = acc;
    }
}

__global__ __launch_bounds__(256) void k_build(const int* __restrict__ tg_idx,
                                               const float* __restrict__ tg_gate,
                                               int* __restrict__ meta,
                                               int* __restrict__ tos,
                                               float* __restrict__ gos) {
    int t = blockIdx.x * 256 + threadIdx.x;
#pragma unroll
    for (int kk = 0; kk < 2; kk++) {
        int e = tg_idx[t * 2 + kk];
        int pos = atomicAdd(&meta[8 + e], 1);
        int slot = meta[24 + e] + pos;
        tos[slot] = t;
        gos[slot] = tg_gate[t * 2 + kk];
    }
}

__global__ __launch_bounds__(256) void k_gather(const float* __restrict__ x,
                                                const int* __restrict__ tos,
                                                const int* __restrict__ meta,
                                                unsigned short* __restrict__ xg) {
    int s = blockIdx.x;
    if (s >= meta[33]) return;
    int t = tos[s];
    int tid = threadIdx.x;
#pragma unroll
    for (int j = 0; j < 4; j++) {
        int k = tid + j * 256;
        float v = (t >= 0) ? x[(size_t)t * DMODEL + k] : 0.f;
        xg[(size_t)s * DMODEL + k] = f2bf(v);
    }
}

// in: [E][R][C] fp32 -> out: [E][C][R] bf16
__global__ __launch_bounds__(256) void k_transpose(const float* __restrict__ in,
                                                   unsigned short* __restrict__ out,
                                                   int R, int C) {
    __shared__ float tile[32][33];
    int e = blockIdx.z;
    const float* src = in + (size_t)e * R * C;
    unsigned short* dst = out + (size_t)e * R * C;
    int cb = blockIdx.x * 32, rb = blockIdx.y * 32;
    int tx = threadIdx.x & 31, ty = threadIdx.x >> 5; // ty 0..7
#pragma unroll
    for (int j = 0; j < 32; j += 8)
        tile[ty + j][tx] = src[(size_t)(rb + ty + j) * C + cb + tx];
    __syncthreads();
#pragma unroll
    for (int j = 0; j < 32; j += 8)
        dst[(size_t)(cb + ty + j) * R + rb + tx] = f2bf(tile[tx][ty + j]);
}

// MODE 1: h = relu(xg @ W1[e] + b1[e]) -> bf16 H.  MODE 2: out[t] += gate * (h @ W2[e] + b2[e])
template <int MODE>
__global__ __launch_bounds__(256) void k_gemm(const unsigned short* __restrict__ A,
                                              const unsigned short* __restrict__ Bt,
                                              const float* __restrict__ bias,
                                              const int* __restrict__ meta,
                                              const int* __restrict__ tos,
                                              const float* __restrict__ gos,
                                              unsigned short* __restrict__ H,
                                              float* __restrict__ Out) {
    constexpr int K = (MODE == 1) ? DMODEL : DFF;
    constexpr int N = (MODE == 1) ? DFF : DMODEL;

    int e = blockIdx.z, mt = blockIdx.y, nt = blockIdx.x;
    if (mt * 128 >= meta[16 + e]) return;
    int row0 = meta[24 + e] + mt * 128;
    int col0 = nt * 128;
    const unsigned short* Be = Bt + (size_t)e * N * K;
    const float* be = bias + (size_t)e * N;

    __shared__ __align__(16) unsigned short As[128 * 72];
    __shared__ __align__(16) unsigned short Bs[128 * 72];

    int tid = threadIdx.x;
    int lane = tid & 63, wave = tid >> 6;
    int wy = wave >> 1, wx = wave & 1;
    int q = lane >> 4, r16 = lane & 15;

    f32x4 acc[4][4];
#pragma unroll
    for (int i = 0; i < 4; i++)
#pragma unroll
        for (int j = 0; j < 4; j++) acc[i][j] = (f32x4){0.f, 0.f, 0.f, 0.f};

    for (int k0 = 0; k0 < K; k0 += 64) {
        __syncthreads();
#pragma unroll
        for (int rr = 0; rr < 4; rr++) {
            int lin = rr * 256 + tid;
            int arow = lin >> 3, a16 = lin & 7;
            const uint4* ga = (const uint4*)(A + (size_t)(row0 + arow) * K + k0) + a16;
            *(uint4*)&As[arow * 72 + a16 * 8] = *ga;
            const uint4* gb = (const uint4*)(Be + (size_t)(col0 + arow) * K + k0) + a16;
            *(uint4*)&Bs[arow * 72 + a16 * 8] = *gb;
        }
        __syncthreads();
#pragma unroll
        for (int ks = 0; ks < 2; ks++) {
            bf16x8 af[4], bf[4];
#pragma unroll
            for (int i = 0; i < 4; i++)
                af[i] = *(const bf16x8*)&As[(wy * 64 + i * 16 + r16) * 72 + ks * 32 + q * 8];
#pragma unroll
            for (int j = 0; j < 4; j++)
                bf[j] = *(const bf16x8*)&Bs[(wx * 64 + j * 16 + r16) * 72 + ks * 32 + q * 8];
#pragma unroll
            for (int i = 0; i < 4; i++)
#pragma unroll
                for (int j = 0; j < 4; j++)
                    acc[i][j] = __builtin_amdgcn_mfma_f32_16x16x32_bf16(af[i], bf[j], acc[i][j], 0, 0, 0);
        }
    }

    if constexpr (MODE == 1) {
#pragma unroll
        for (int i = 0; i < 4; i++) {
#pragma unroll
            for (int rr = 0; rr < 4; rr++) {
                int gs = row0 + wy * 64 + i * 16 + q * 4 + rr;
#pragma unroll
                for (int j = 0; j < 4; j++) {
                    int gn = col0 + wx * 64 + j * 16 + r16;
                    float v = acc[i][j][rr] + be[gn];
                    H[(size_t)gs * DFF + gn] = f2bf(v > 0.f ? v : 0.f);
                }
            }
        }
    } else {
#pragma unroll
        for (int i = 0; i < 4; i++) {
#pragma unroll
            for (int rr = 0; rr < 4; rr++) {
                int gs = row0 + wy * 64 + i * 16 + q * 4 + rr;
                int t = tos[gs];
                if (t < 0) continue;
                float g = gos[gs];
#pragma unroll
                for (int j = 0; j < 4; j++) {
                    int gn = col0 + wx * 64 + j * 16 + r16;
                    atomicAdd(&Out[(size_t)t * DMODEL + gn], g * (acc[i][j][rr] + be[gn]));
                }
            }
        }
    }
}

extern "C" void kernel_launch(void* const* d_in, const int* in_sizes, int n_in,
                              void* d_out, int out_size, void* d_ws, size_t ws_size,
                              hipStream_t stream) {
    const float* x  = (const float*)d_in[0];
    const float* Wr = (const float*)d_in[1];
    const float* W1 = (const float*)d_in[2];
    const float* b1 = (const float*)d_in[3];
    const float* W2 = (const float*)d_in[4];
    const float* b2 = (const float*)d_in[5];
    float* out = (float*)d_out;

    char* p = (char*)d_ws;
    auto alloc = [&](size_t bytes) {
        char* q = p;
        p += (bytes + 255) & ~(size_t)255;
        return q;
    };
    int*   meta    = (int*)alloc(64 * 4);
    int*   tg_idx  = (int*)alloc((size_t)T_TOK * 2 * 4);
    float* tg_gate = (float*)alloc((size_t)T_TOK * 2 * 4);
    int*   tos     = (int*)alloc((size_t)CAP * 4);
    float* gos     = (float*)alloc((size_t)CAP * 4);
    unsigned short* W1t = (unsigned short*)alloc((size_t)NE * DMODEL * DFF * 2);
    unsigned short* W2t = (unsigned short*)alloc((size_t)NE * DMODEL * DFF * 2);
    unsigned short* xg  = (unsigned short*)alloc((size_t)CAP * DMODEL * 2);
    unsigned short* h   = (unsigned short*)alloc((size_t)CAP * DFF * 2);

    hipMemsetAsync(meta, 0, 64 * 4, stream);
    hipMemsetAsync(tos, 0xFF, (size_t)CAP * 4, stream);  // token_of_slot = -1 (padding)
    hipMemsetAsync(d_out, 0, (size_t)out_size * 4, stream);

    k_router<<<T_TOK / 4, 256, 0, stream>>>(x, Wr, meta, tg_idx, tg_gate);
    k_scan<<<1, 64, 0, stream>>>(meta);
    k_build<<<T_TOK / 256, 256, 0, stream>>>(tg_idx, tg_gate, meta, tos, gos);
    k_gather<<<CAP, 256, 0, stream>>>(x, tos, meta, xg);
    k_transpose<<<dim3(DFF / 32, DMODEL / 32, NE), 256, 0, stream>>>(W1, W1t, DMODEL, DFF);
    k_transpose<<<dim3(DMODEL / 32, DFF / 32, NE), 256, 0, stream>>>(W2, W2t, DFF, DMODEL);
    k_gemm<1><<<dim3(DFF / 128, MT_CAP, NE), 256, 0, stream>>>(xg, W1t, b1, meta, tos, gos, h, nullptr);
    k_gemm<2><<<dim3(DMODEL / 128, MT_CAP, NE), 256, 0, stream>>>(h, W2t, b2, meta, tos, gos, nullptr, out);
}

// Round 2
// 707.666 us; speedup vs baseline: 1.1920x; 1.1920x over previous
//
#include <hip/hip_runtime.h>

// MoE top-2, D=1024, DFF=4096, E=8, T=4096. Sparse grouped-GEMM, bf16 MFMA,
// m97-style global_load_lds staging with XOR-swizzled LDS layout.

#define T_TOK 4096
#define DMODEL 1024
#define DFF 4096
#define NE 8
#define CAP 9216            // max aligned slots: 8192 + 8*127 -> 9208, padded
#define MT_CAP (CAP / 128)  // 72

typedef __bf16 bf16x8 __attribute__((ext_vector_type(8)));
typedef float f32x4 __attribute__((ext_vector_type(4)));

__device__ __forceinline__ unsigned short f2bf(float f) {
    union { float f; unsigned u; } v; v.f = f;
    unsigned r = v.u + 0x7fffu + ((v.u >> 16) & 1u);
    return (unsigned short)(r >> 16);
}

// async 16B/lane global->LDS. LDS dest = base + lane*16 (wave-uniform base).
__device__ __forceinline__ void gld16(const unsigned short* g, unsigned short* l) {
    __builtin_amdgcn_global_load_lds(
        (const __attribute__((address_space(1))) unsigned int*)g,
        (__attribute__((address_space(3))) unsigned int*)l, 16, 0, 0);
}

// meta layout (ints): [0..7] count, [8..15] cursor, [16..23] aligned, [24..32] off[9], [33] total
__global__ __launch_bounds__(256) void k_router(const float* __restrict__ x,
                                                const float* __restrict__ Wr,
                                                int* __restrict__ meta,
                                                int* __restrict__ tg_idx,
                                                float* __restrict__ tg_gate) {
    int wave = threadIdx.x >> 6, lane = threadIdx.x & 63;
    int t = blockIdx.x * 4 + wave;
    double acc[NE];
#pragma unroll
    for (int e = 0; e < NE; e++) acc[e] = 0.0;
    const float* xr = x + (size_t)t * DMODEL;
#pragma unroll 4
    for (int j = 0; j < 16; j++) {
        int k = j * 64 + lane;
        double xv = (double)xr[k];
        const float4* wr = (const float4*)(Wr + k * NE);
        float4 w0 = wr[0], w1 = wr[1];
        acc[0] += xv * (double)w0.x; acc[1] += xv * (double)w0.y;
        acc[2] += xv * (double)w0.z; acc[3] += xv * (double)w0.w;
        acc[4] += xv * (double)w1.x; acc[5] += xv * (double)w1.y;
        acc[6] += xv * (double)w1.z; acc[7] += xv * (double)w1.w;
    }
#pragma unroll
    for (int off = 32; off; off >>= 1)
#pragma unroll
        for (int e = 0; e < NE; e++) acc[e] += __shfl_xor(acc[e], off);
    if (lane == 0) {
        double v1 = -1e300, v2 = -1e300; int i1 = 0, i2 = 0;
#pragma unroll
        for (int e = 0; e < NE; e++) {
            double v = acc[e];
            if (v > v1) { v2 = v1; i2 = i1; v1 = v; i1 = e; }
            else if (v > v2) { v2 = v; i2 = e; }
        }
        double g1 = 1.0 / (1.0 + exp(v2 - v1));
        tg_idx[t * 2] = i1; tg_idx[t * 2 + 1] = i2;
        tg_gate[t * 2] = (float)g1; tg_gate[t * 2 + 1] = (float)(1.0 - g1);
        atomicAdd(&meta[i1], 1);
        atomicAdd(&meta[i2], 1);
    }
}

__global__ void k_scan(int* __restrict__ meta) {
    if (threadIdx.x == 0) {
        int acc = 0;
        for (int e = 0; e < NE; e++) {
            int a = (meta[e] + 127) & ~127;
            meta[16 + e] = a;
            meta[24 + e] = acc;
            acc += a;
        }
        meta[24 + NE] = acc;
        meta[33] = acc;
    }
}

__global__ __launch_bounds__(256) void k_build(const int* __restrict__ tg_idx,
                                               const float* __restrict__ tg_gate,
                                               int* __restrict__ meta,
                                               int* __restrict__ tos,
                                               float* __restrict__ gos,
                                               int* __restrict__ sot) {
    int t = blockIdx.x * 256 + threadIdx.x;
#pragma unroll
    for (int kk = 0; kk < 2; kk++) {
        int e = tg_idx[t * 2 + kk];
        int pos = atomicAdd(&meta[8 + e], 1);
        int slot = meta[24 + e] + pos;
        tos[slot] = t;
        gos[slot] = tg_gate[t * 2 + kk];
        sot[t * 2 + kk] = slot;
    }
}

__global__ __launch_bounds__(256) void k_gather(const float* __restrict__ x,
                                                const int* __restrict__ tos,
                                                const int* __restrict__ meta,
                                                unsigned short* __restrict__ xg) {
    int s = blockIdx.x;
    if (s >= meta[33]) return;
    int t = tos[s];
    int tid = threadIdx.x;
#pragma unroll
    for (int j = 0; j < 4; j++) {
        int k = tid + j * 256;
        float v = (t >= 0) ? x[(size_t)t * DMODEL + k] : 0.f;
        xg[(size_t)s * DMODEL + k] = f2bf(v);
    }
}

// in: [E][R][C] fp32 -> out: [E][C][R] bf16. Register 4x4 transpose, no LDS.
__global__ __launch_bounds__(256) void k_transpose(const float* __restrict__ in,
                                                   unsigned short* __restrict__ out,
                                                   int R, int C) {
    int e = blockIdx.z;
    const float* src = in + (size_t)e * R * C;
    unsigned short* dst = out + (size_t)e * R * C;
    int rb = blockIdx.y * 64 + (threadIdx.x >> 4) * 4;
    int cb = blockIdx.x * 64 + (threadIdx.x & 15) * 4;
    f32x4 v[4];
#pragma unroll
    for (int i = 0; i < 4; i++)
        v[i] = *(const f32x4*)&src[(size_t)(rb + i) * C + cb];
#pragma unroll
    for (int j = 0; j < 4; j++) {
        unsigned short o[4];
#pragma unroll
        for (int i = 0; i < 4; i++) o[i] = f2bf(v[i][j]);
        *(uint2*)&dst[(size_t)(cb + j) * R + rb] = *(uint2*)o;
    }
}

// MODE 1: h = relu(xg @ W1t[e] + b1[e]) -> bf16 H.
// MODE 2: y[split][slot] = h @ W2t[e]   (split-K=2, bias+gate in combine)
// LDS layout: row-major stride 64 shorts, chunk slot c of row r holds global
// k-chunk (c ^ (r&7)) -- XOR swizzle applied on the global address so the
// lane-contiguous global_load_lds dest stays legal AND ds_read_b128 fragment
// reads are bank-conflict-free.
template <int MODE>
__global__ __launch_bounds__(256, 4) void k_gemm(const unsigned short* __restrict__ A,
                                                 const unsigned short* __restrict__ Bt,
                                                 const float* __restrict__ bias,
                                                 const int* __restrict__ meta,
                                                 unsigned short* __restrict__ H,
                                                 float* __restrict__ Y) {
    constexpr int KFULL = (MODE == 1) ? DMODEL : DFF;
    constexpr int K     = (MODE == 1) ? DMODEL : DFF / 2;  // MODE2: split-K half
    constexpr int N     = (MODE == 1) ? DFF : DMODEL;

    int zz = blockIdx.z;
    int e  = (MODE == 1) ? zz : (zz >> 1);
    int kq = (MODE == 1) ? 0 : (zz & 1);
    if (blockIdx.y * 128 >= meta[16 + e]) return;
    int row0 = meta[24 + e] + blockIdx.y * 128;
    int col0 = blockIdx.x * 128;
    const unsigned short* Ae = A + (size_t)row0 * KFULL + kq * K;
    const unsigned short* Be = Bt + (size_t)e * N * KFULL + (size_t)col0 * KFULL + kq * K;
    const float* be = bias + (size_t)e * N;

    __shared__ __align__(16) unsigned short As[128 * 64];
    __shared__ __align__(16) unsigned short Bs[128 * 64];

    int tid = threadIdx.x;
    int lane = tid & 63, wave = tid >> 6;
    int wy = wave >> 1, wx = wave & 1;
    int q = lane >> 4, r16 = lane & 15;

    int srow = lane >> 3;                 // row within 8-row instr group
    int schunk = (lane & 7) ^ srow;       // swizzled global k-chunk for this lane
    int sgoff = srow * KFULL + schunk * 8;  // global short-offset within instr group

    f32x4 acc[4][4];
#pragma unroll
    for (int i = 0; i < 4; i++)
#pragma unroll
        for (int j = 0; j < 4; j++) acc[i][j] = (f32x4){0.f, 0.f, 0.f, 0.f};

    for (int k0 = 0; k0 < K; k0 += 64) {
        __syncthreads();
#pragma unroll
        for (int it = 0; it < 4; it++) {
            int gr = wave * 32 + it * 8;  // base row of this instr group
            gld16(Ae + (size_t)gr * KFULL + k0 + sgoff, &As[gr * 64]);
            gld16(Be + (size_t)gr * KFULL + k0 + sgoff, &Bs[gr * 64]);
        }
        __syncthreads();
#pragma unroll
        for (int ks = 0; ks < 2; ks++) {
            bf16x8 af[4], bfr[4];
            int sw = (r16 & 7);
#pragma unroll
            for (int i = 0; i < 4; i++) {
                int m = wy * 64 + i * 16 + r16;
                af[i] = *(const bf16x8*)&As[m * 64 + (((ks * 4 + q) ^ sw) << 3)];
            }
#pragma unroll
            for (int j = 0; j < 4; j++) {
                int n = wx * 64 + j * 16 + r16;
                bfr[j] = *(const bf16x8*)&Bs[n * 64 + (((ks * 4 + q) ^ sw) << 3)];
            }
#pragma unroll
            for (int i = 0; i < 4; i++)
#pragma unroll
                for (int j = 0; j < 4; j++)
                    acc[i][j] = __builtin_amdgcn_mfma_f32_16x16x32_bf16(af[i], bfr[j], acc[i][j], 0, 0, 0);
        }
    }

    if constexpr (MODE == 1) {
#pragma unroll
        for (int i = 0; i < 4; i++) {
#pragma unroll
            for (int rr = 0; rr < 4; rr++) {
                int gs = row0 + wy * 64 + i * 16 + q * 4 + rr;
#pragma unroll
                for (int j = 0; j < 4; j++) {
                    int gn = col0 + wx * 64 + j * 16 + r16;
                    float v = acc[i][j][rr] + be[gn];
                    H[(size_t)gs * DFF + gn] = f2bf(v > 0.f ? v : 0.f);
                }
            }
        }
    } else {
        float* Yp = Y + (size_t)kq * CAP * DMODEL;
#pragma unroll
        for (int i = 0; i < 4; i++) {
#pragma unroll
            for (int rr = 0; rr < 4; rr++) {
                int gs = row0 + wy * 64 + i * 16 + q * 4 + rr;
#pragma unroll
                for (int j = 0; j < 4; j++) {
                    int gn = col0 + wx * 64 + j * 16 + r16;
                    Yp[(size_t)gs * DMODEL + gn] = acc[i][j][rr];
                }
            }
        }
    }
}

// out[t] = g0*(y0[s0]+y1[s0]+b2[e0]) + g1*(y0[s1]+y1[s1]+b2[e1])
__global__ __launch_bounds__(256) void k_combine(const float* __restrict__ Y,
                                                 const int* __restrict__ tg_idx,
                                                 const float* __restrict__ tg_gate,
                                                 const int* __restrict__ sot,
                                                 const float* __restrict__ b2,
                                                 float* __restrict__ out) {
    int t = blockIdx.x;
    int e0 = tg_idx[t * 2], e1 = tg_idx[t * 2 + 1];
    float g0 = tg_gate[t * 2], g1 = tg_gate[t * 2 + 1];
    int s0 = sot[t * 2], s1 = sot[t * 2 + 1];
    const float* y0 = Y;
    const float* y1 = Y + (size_t)CAP * DMODEL;
    int d = threadIdx.x * 4;
    f32x4 a0 = *(const f32x4*)&y0[(size_t)s0 * DMODEL + d];
    f32x4 b0 = *(const f32x4*)&y1[(size_t)s0 * DMODEL + d];
    f32x4 a1 = *(const f32x4*)&y0[(size_t)s1 * DMODEL + d];
    f32x4 b1v = *(const f32x4*)&y1[(size_t)s1 * DMODEL + d];
    f32x4 c0 = *(const f32x4*)&b2[(size_t)e0 * DMODEL + d];
    f32x4 c1 = *(const f32x4*)&b2[(size_t)e1 * DMODEL + d];
    f32x4 r;
#pragma unroll
    for (int i = 0; i < 4; i++)
        r[i] = g0 * (a0[i] + b0[i] + c0[i]) + g1 * (a1[i] + b1v[i] + c1[i]);
    *(f32x4*)&out[(size_t)t * DMODEL + d] = r;
}

extern "C" void kernel_launch(void* const* d_in, const int* in_sizes, int n_in,
                              void* d_out, int out_size, void* d_ws, size_t ws_size,
                              hipStream_t stream) {
    const float* x  = (const float*)d_in[0];
    const float* Wr = (const float*)d_in[1];
    const float* W1 = (const float*)d_in[2];
    const float* b1 = (const float*)d_in[3];
    const float* W2 = (const float*)d_in[4];
    const float* b2 = (const float*)d_in[5];
    float* out = (float*)d_out;

    char* p = (char*)d_ws;
    auto alloc = [&](size_t bytes) {
        char* q = p;
        p += (bytes + 255) & ~(size_t)255;
        return q;
    };
    int*   meta    = (int*)alloc(64 * 4);
    int*   tg_idx  = (int*)alloc((size_t)T_TOK * 2 * 4);
    float* tg_gate = (float*)alloc((size_t)T_TOK * 2 * 4);
    int*   tos     = (int*)alloc((size_t)CAP * 4);
    float* gos     = (float*)alloc((size_t)CAP * 4);
    int*   sot     = (int*)alloc((size_t)T_TOK * 2 * 4);
    unsigned short* xg  = (unsigned short*)alloc((size_t)CAP * DMODEL * 2);
    unsigned short* W1t = (unsigned short*)alloc((size_t)NE * DMODEL * DFF * 2);
    unsigned short* W2t = (unsigned short*)alloc((size_t)NE * DMODEL * DFF * 2);
    unsigned short* h   = (unsigned short*)alloc((size_t)CAP * DFF * 2);
    // y (2 x CAP x DMODEL fp32 = 75.5 MB) aliases xg+W1t (83 MB): both are dead
    // by the time GEMM2 writes y (GEMM2 reads only h, W2t, meta).
    float* y = (float*)xg;

    hipMemsetAsync(meta, 0, 64 * 4, stream);
    hipMemsetAsync(tos, 0xFF, (size_t)CAP * 4, stream);  // pad slots -> t=-1

    k_router<<<T_TOK / 4, 256, 0, stream>>>(x, Wr, meta, tg_idx, tg_gate);
    k_scan<<<1, 64, 0, stream>>>(meta);
    k_build<<<T_TOK / 256, 256, 0, stream>>>(tg_idx, tg_gate, meta, tos, gos, sot);
    k_gather<<<CAP, 256, 0, stream>>>(x, tos, meta, xg);
    k_transpose<<<dim3(DFF / 64, DMODEL / 64, NE), 256, 0, stream>>>(W1, W1t, DMODEL, DFF);
    k_transpose<<<dim3(DMODEL / 64, DFF / 64, NE), 256, 0, stream>>>(W2, W2t, DFF, DMODEL);
    k_gemm<1><<<dim3(DFF / 128, MT_CAP, NE), 256, 0, stream>>>(xg, W1t, b1, meta, h, nullptr);
    k_gemm<2><<<dim3(DMODEL / 128, MT_CAP, NE * 2), 256, 0, stream>>>(h, W2t, b2, meta, nullptr, y);
    k_combine<<<T_TOK, 256, 0, stream>>>(y, tg_idx, tg_gate, sot, b2, out);
}

// Round 3
// 694.177 us; speedup vs baseline: 1.2152x; 1.0194x over previous
//
#include <hip/hip_runtime.h>

// MoE top-2, D=1024, DFF=4096, E=8, T=4096. Sparse grouped-GEMM, bf16 MFMA,
// global_load_lds staging, XOR-swizzled LDS, XCD-pinned strip-major schedule.

#define T_TOK 4096
#define DMODEL 1024
#define DFF 4096
#define NE 8
#define CAP 9216            // max aligned slots: 8192 + 8*127 -> 9208, padded
#define MT_CAP (CAP / 128)  // 72

typedef __bf16 bf16x8 __attribute__((ext_vector_type(8)));
typedef float f32x4 __attribute__((ext_vector_type(4)));

__device__ __forceinline__ unsigned short f2bf(float f) {
    union { float f; unsigned u; } v; v.f = f;
    unsigned r = v.u + 0x7fffu + ((v.u >> 16) & 1u);
    return (unsigned short)(r >> 16);
}

// async 16B/lane global->LDS. LDS dest = base + lane*16 (wave-uniform base).
__device__ __forceinline__ void gld16(const unsigned short* g, unsigned short* l) {
    __builtin_amdgcn_global_load_lds(
        (const __attribute__((address_space(1))) unsigned int*)g,
        (__attribute__((address_space(3))) unsigned int*)l, 16, 0, 0);
}

// meta layout (ints): [0..7] count, [8..15] cursor, [16..23] aligned, [24..32] off[9], [33] total
__global__ __launch_bounds__(256) void k_router(const float* __restrict__ x,
                                                const float* __restrict__ Wr,
                                                int* __restrict__ meta,
                                                int* __restrict__ tg_idx,
                                                float* __restrict__ tg_gate) {
    int wave = threadIdx.x >> 6, lane = threadIdx.x & 63;
    int t = blockIdx.x * 4 + wave;
    double acc[NE];
#pragma unroll
    for (int e = 0; e < NE; e++) acc[e] = 0.0;
    const float* xr = x + (size_t)t * DMODEL;
#pragma unroll 4
    for (int j = 0; j < 16; j++) {
        int k = j * 64 + lane;
        double xv = (double)xr[k];
        const float4* wr = (const float4*)(Wr + k * NE);
        float4 w0 = wr[0], w1 = wr[1];
        acc[0] += xv * (double)w0.x; acc[1] += xv * (double)w0.y;
        acc[2] += xv * (double)w0.z; acc[3] += xv * (double)w0.w;
        acc[4] += xv * (double)w1.x; acc[5] += xv * (double)w1.y;
        acc[6] += xv * (double)w1.z; acc[7] += xv * (double)w1.w;
    }
#pragma unroll
    for (int off = 32; off; off >>= 1)
#pragma unroll
        for (int e = 0; e < NE; e++) acc[e] += __shfl_xor(acc[e], off);
    if (lane == 0) {
        double v1 = -1e300, v2 = -1e300; int i1 = 0, i2 = 0;
#pragma unroll
        for (int e = 0; e < NE; e++) {
            double v = acc[e];
            if (v > v1) { v2 = v1; i2 = i1; v1 = v; i1 = e; }
            else if (v > v2) { v2 = v; i2 = e; }
        }
        double g1 = 1.0 / (1.0 + exp(v2 - v1));
        tg_idx[t * 2] = i1; tg_idx[t * 2 + 1] = i2;
        tg_gate[t * 2] = (float)g1; tg_gate[t * 2 + 1] = (float)(1.0 - g1);
        atomicAdd(&meta[i1], 1);
        atomicAdd(&meta[i2], 1);
    }
}

__global__ void k_scan(int* __restrict__ meta) {
    if (threadIdx.x == 0) {
        int acc = 0;
        for (int e = 0; e < NE; e++) {
            int a = (meta[e] + 127) & ~127;
            meta[16 + e] = a;
            meta[24 + e] = acc;
            acc += a;
        }
        meta[24 + NE] = acc;
        meta[33] = acc;
    }
}

__global__ __launch_bounds__(256) void k_build(const int* __restrict__ tg_idx,
                                               const float* __restrict__ tg_gate,
                                               int* __restrict__ meta,
                                               int* __restrict__ tos,
                                               float* __restrict__ gos,
                                               int* __restrict__ sot) {
    int t = blockIdx.x * 256 + threadIdx.x;
#pragma unroll
    for (int kk = 0; kk < 2; kk++) {
        int e = tg_idx[t * 2 + kk];
        int pos = atomicAdd(&meta[8 + e], 1);
        int slot = meta[24 + e] + pos;
        tos[slot] = t;
        gos[slot] = tg_gate[t * 2 + kk];
        sot[t * 2 + kk] = slot;
    }
}

__global__ __launch_bounds__(256) void k_gather(const float* __restrict__ x,
                                                const int* __restrict__ tos,
                                                const int* __restrict__ meta,
                                                unsigned short* __restrict__ xg) {
    int s = blockIdx.x;
    if (s >= meta[33]) return;
    int t = tos[s];
    int tid = threadIdx.x;
#pragma unroll
    for (int j = 0; j < 4; j++) {
        int k = tid + j * 256;
        float v = (t >= 0) ? x[(size_t)t * DMODEL + k] : 0.f;
        xg[(size_t)s * DMODEL + k] = f2bf(v);
    }
}

// in: [E][R][C] fp32 -> out: [E][C][R] bf16.
// Register 8x4 blocks: reads 8x 128-B segments/wave, writes 8x 128-B segments/wave.
__global__ __launch_bounds__(256) void k_transpose(const float* __restrict__ in,
                                                   unsigned short* __restrict__ out,
                                                   int R, int C) {
    int e = blockIdx.z;
    const float* src = in + (size_t)e * R * C;
    unsigned short* dst = out + (size_t)e * R * C;
    int g = threadIdx.x >> 3, l8 = threadIdx.x & 7;
    int rb = blockIdx.y * 64 + l8 * 8;       // 8 rows per thread
    int cb = blockIdx.x * 128 + g * 4;       // 4 cols per thread
    f32x4 v[8];
#pragma unroll
    for (int i = 0; i < 8; i++)
        v[i] = *(const f32x4*)&src[(size_t)(rb + i) * C + cb];
#pragma unroll
    for (int j = 0; j < 4; j++) {
        unsigned short o[8];
#pragma unroll
        for (int i = 0; i < 8; i++) o[i] = f2bf(v[i][j]);
        *(uint4*)&dst[(size_t)(cb + j) * R + rb] = *(uint4*)o;
    }
}

// MODE 1: h = relu(xg @ W1t[e] + b1[e]) -> bf16 H.
// MODE 2: y[split][slot] = h @ W2t[e]   (split-K=2, bias+gate in combine)
// 1D grid, strip-major XCD-pinned: xcd = L&7; all mtiles of one weight strip
// (fixed e,nt[,kq]) run on one XCD so the 256-512 KB B-strip stays in its L2.
// LDS: row stride 64 shorts, chunk c of row r holds k-chunk c^(r&7) (swizzle
// applied on the global address; ds_read_b128 fragment reads conflict-free).
template <int MODE>
__global__ __launch_bounds__(256, 4) void k_gemm(const unsigned short* __restrict__ A,
                                                 const unsigned short* __restrict__ Bt,
                                                 const float* __restrict__ bias,
                                                 const int* __restrict__ meta,
                                                 unsigned short* __restrict__ H,
                                                 float* __restrict__ Y) {
    constexpr int KFULL = (MODE == 1) ? DMODEL : DFF;
    constexpr int K     = (MODE == 1) ? DMODEL : DFF / 2;  // MODE2: split-K half
    constexpr int N     = (MODE == 1) ? DFF : DMODEL;

    int L = blockIdx.x;
    int xcd = L & 7, c = L >> 3;
    int sgrp = c / MT_CAP, mt = c - sgrp * MT_CAP;
    int s = (sgrp << 3) | xcd;
    int e, kq, nt;
    if constexpr (MODE == 1) { e = s >> 5; nt = s & 31; kq = 0; }
    else                     { e = s >> 4; kq = (s >> 3) & 1; nt = s & 7; }
    if (mt * 128 >= meta[16 + e]) return;
    int row0 = meta[24 + e] + mt * 128;
    int col0 = nt * 128;
    const unsigned short* Ae = A + (size_t)row0 * KFULL + kq * K;
    const unsigned short* Be = Bt + (size_t)e * N * KFULL + (size_t)col0 * KFULL + kq * K;
    const float* be = bias + (size_t)e * N;

    __shared__ __align__(16) unsigned short As[128 * 64];
    __shared__ __align__(16) unsigned short Bs[128 * 64];

    int tid = threadIdx.x;
    int lane = tid & 63, wave = tid >> 6;
    int wy = wave >> 1, wx = wave & 1;
    int q = lane >> 4, r16 = lane & 15;

    int srow = lane >> 3;                 // row within 8-row instr group
    int schunk = (lane & 7) ^ srow;       // swizzled global k-chunk for this lane
    int sgoff = srow * KFULL + schunk * 8;  // global short-offset within instr group

    f32x4 acc[4][4];
#pragma unroll
    for (int i = 0; i < 4; i++)
#pragma unroll
        for (int j = 0; j < 4; j++) acc[i][j] = (f32x4){0.f, 0.f, 0.f, 0.f};

    for (int k0 = 0; k0 < K; k0 += 64) {
        __syncthreads();
#pragma unroll
        for (int it = 0; it < 4; it++) {
            int gr = wave * 32 + it * 8;  // base row of this instr group
            gld16(Ae + (size_t)gr * KFULL + k0 + sgoff, &As[gr * 64]);
            gld16(Be + (size_t)gr * KFULL + k0 + sgoff, &Bs[gr * 64]);
        }
        __syncthreads();
#pragma unroll
        for (int ks = 0; ks < 2; ks++) {
            bf16x8 af[4], bfr[4];
            int sw = (r16 & 7);
#pragma unroll
            for (int i = 0; i < 4; i++) {
                int m = wy * 64 + i * 16 + r16;
                af[i] = *(const bf16x8*)&As[m * 64 + (((ks * 4 + q) ^ sw) << 3)];
            }
#pragma unroll
            for (int j = 0; j < 4; j++) {
                int n = wx * 64 + j * 16 + r16;
                bfr[j] = *(const bf16x8*)&Bs[n * 64 + (((ks * 4 + q) ^ sw) << 3)];
            }
#pragma unroll
            for (int i = 0; i < 4; i++)
#pragma unroll
                for (int j = 0; j < 4; j++)
                    acc[i][j] = __builtin_amdgcn_mfma_f32_16x16x32_bf16(af[i], bfr[j], acc[i][j], 0, 0, 0);
        }
    }

    if constexpr (MODE == 1) {
#pragma unroll
        for (int i = 0; i < 4; i++) {
#pragma unroll
            for (int rr = 0; rr < 4; rr++) {
                int gs = row0 + wy * 64 + i * 16 + q * 4 + rr;
#pragma unroll
                for (int j = 0; j < 4; j++) {
                    int gn = col0 + wx * 64 + j * 16 + r16;
                    float v = acc[i][j][rr] + be[gn];
                    H[(size_t)gs * DFF + gn] = f2bf(v > 0.f ? v : 0.f);
                }
            }
        }
    } else {
        float* Yp = Y + (size_t)kq * CAP * DMODEL;
#pragma unroll
        for (int i = 0; i < 4; i++) {
#pragma unroll
            for (int rr = 0; rr < 4; rr++) {
                int gs = row0 + wy * 64 + i * 16 + q * 4 + rr;
#pragma unroll
                for (int j = 0; j < 4; j++) {
                    int gn = col0 + wx * 64 + j * 16 + r16;
                    Yp[(size_t)gs * DMODEL + gn] = acc[i][j][rr];
                }
            }
        }
    }
}

// out[t] = g0*(y0[s0]+y1[s0]+b2[e0]) + g1*(y0[s1]+y1[s1]+b2[e1])
__global__ __launch_bounds__(256) void k_combine(const float* __restrict__ Y,
                                                 const int* __restrict__ tg_idx,
                                                 const float* __restrict__ tg_gate,
                                                 const int* __restrict__ sot,
                                                 const float* __restrict__ b2,
                                                 float* __restrict__ out) {
    int t = blockIdx.x;
    int e0 = tg_idx[t * 2], e1 = tg_idx[t * 2 + 1];
    float g0 = tg_gate[t * 2], g1 = tg_gate[t * 2 + 1];
    int s0 = sot[t * 2], s1 = sot[t * 2 + 1];
    const float* y0 = Y;
    const float* y1 = Y + (size_t)CAP * DMODEL;
    int d = threadIdx.x * 4;
    f32x4 a0 = *(const f32x4*)&y0[(size_t)s0 * DMODEL + d];
    f32x4 b0 = *(const f32x4*)&y1[(size_t)s0 * DMODEL + d];
    f32x4 a1 = *(const f32x4*)&y0[(size_t)s1 * DMODEL + d];
    f32x4 b1v = *(const f32x4*)&y1[(size_t)s1 * DMODEL + d];
    f32x4 c0 = *(const f32x4*)&b2[(size_t)e0 * DMODEL + d];
    f32x4 c1 = *(const f32x4*)&b2[(size_t)e1 * DMODEL + d];
    f32x4 r;
#pragma unroll
    for (int i = 0; i < 4; i++)
        r[i] = g0 * (a0[i] + b0[i] + c0[i]) + g1 * (a1[i] + b1v[i] + c1[i]);
    *(f32x4*)&out[(size_t)t * DMODEL + d] = r;
}

extern "C" void kernel_launch(void* const* d_in, const int* in_sizes, int n_in,
                              void* d_out, int out_size, void* d_ws, size_t ws_size,
                              hipStream_t stream) {
    const float* x  = (const float*)d_in[0];
    const float* Wr = (const float*)d_in[1];
    const float* W1 = (const float*)d_in[2];
    const float* b1 = (const float*)d_in[3];
    const float* W2 = (const float*)d_in[4];
    const float* b2 = (const float*)d_in[5];
    float* out = (float*)d_out;

    char* p = (char*)d_ws;
    auto alloc = [&](size_t bytes) {
        char* q = p;
        p += (bytes + 255) & ~(size_t)255;
        return q;
    };
    int*   meta    = (int*)alloc(64 * 4);
    int*   tg_idx  = (int*)alloc((size_t)T_TOK * 2 * 4);
    float* tg_gate = (float*)alloc((size_t)T_TOK * 2 * 4);
    int*   tos     = (int*)alloc((size_t)CAP * 4);
    float* gos     = (float*)alloc((size_t)CAP * 4);
    int*   sot     = (int*)alloc((size_t)T_TOK * 2 * 4);
    unsigned short* xg  = (unsigned short*)alloc((size_t)CAP * DMODEL * 2);
    unsigned short* W1t = (unsigned short*)alloc((size_t)NE * DMODEL * DFF * 2);
    unsigned short* W2t = (unsigned short*)alloc((size_t)NE * DMODEL * DFF * 2);
    unsigned short* h   = (unsigned short*)alloc((size_t)CAP * DFF * 2);
    // y (2 x CAP x DMODEL fp32 = 75.5 MB) aliases xg+W1t (83 MB): both are dead
    // by the time GEMM2 writes y (GEMM2 reads only h, W2t, meta).
    float* y = (float*)xg;

    hipMemsetAsync(meta, 0, 64 * 4, stream);
    hipMemsetAsync(tos, 0xFF, (size_t)CAP * 4, stream);  // pad slots -> t=-1

    k_router<<<T_TOK / 4, 256, 0, stream>>>(x, Wr, meta, tg_idx, tg_gate);
    k_scan<<<1, 64, 0, stream>>>(meta);
    k_build<<<T_TOK / 256, 256, 0, stream>>>(tg_idx, tg_gate, meta, tos, gos, sot);
    k_gather<<<CAP, 256, 0, stream>>>(x, tos, meta, xg);
    // W1 transpose right before GEMM1, W2 transpose after it: each GEMM runs
    // against an L3 still warm with its own (bf16) weights.
    k_transpose<<<dim3(DFF / 128, DMODEL / 64, NE), 256, 0, stream>>>(W1, W1t, DMODEL, DFF);
    k_gemm<1><<<dim3(NE * (DFF / 128) * MT_CAP), 256, 0, stream>>>(xg, W1t, b1, meta, h, nullptr);
    k_transpose<<<dim3(DMODEL / 128, DFF / 64, NE), 256, 0, stream>>>(W2, W2t, DFF, DMODEL);
    k_gemm<2><<<dim3(NE * 2 * (DMODEL / 128) * MT_CAP), 256, 0, stream>>>(h, W2t, b2, meta, nullptr, y);
    k_combine<<<T_TOK, 256, 0, stream>>>(y, tg_idx, tg_gate, sot, b2, out);
}